// Round 2
// baseline (22326.996 us; speedup 1.0000x reference)
//
#include <hip/hip_runtime.h>

#define N_NODES 100000
#define N_EDGES 1600000
#define FDIM 128
#define GDIM 64
#define CDIM 10

// ---------------- CSR build ----------------
__global__ void k_hist(const int* __restrict__ dst, int* __restrict__ cnt) {
  int e = blockIdx.x * 256 + threadIdx.x;
  if (e < N_EDGES) atomicAdd(&cnt[dst[e]], 1);
}

__global__ void k_scan_blk(const int* __restrict__ cnt, int* __restrict__ incl,
                           int* __restrict__ blk_sums) {
  __shared__ int smem[1024];
  int i = blockIdx.x * 1024 + threadIdx.x;
  int v = (i < N_NODES) ? cnt[i] : 0;
  smem[threadIdx.x] = v;
  __syncthreads();
  for (int off = 1; off < 1024; off <<= 1) {
    int t = (threadIdx.x >= off) ? smem[threadIdx.x - off] : 0;
    __syncthreads();
    smem[threadIdx.x] += t;
    __syncthreads();
  }
  if (i < N_NODES) incl[i] = smem[threadIdx.x];
  if (threadIdx.x == 1023) blk_sums[blockIdx.x] = smem[1023];
}

__global__ void k_scan_sums(int* __restrict__ blk_sums, int* __restrict__ row_ptr,
                            int nblk) {
  __shared__ int smem[128];
  int v = (threadIdx.x < nblk) ? blk_sums[threadIdx.x] : 0;
  smem[threadIdx.x] = v;
  __syncthreads();
  for (int off = 1; off < 128; off <<= 1) {
    int t = (threadIdx.x >= off) ? smem[threadIdx.x - off] : 0;
    __syncthreads();
    smem[threadIdx.x] += t;
    __syncthreads();
  }
  if (threadIdx.x < nblk) blk_sums[threadIdx.x] = smem[threadIdx.x] - v;  // exclusive
  if (threadIdx.x == 127) row_ptr[N_NODES] = smem[127];
}

__global__ void k_scan_final(const int* __restrict__ cnt, int* __restrict__ row_ptr,
                             int* __restrict__ cursor, const int* __restrict__ blk_sums) {
  int i = blockIdx.x * 1024 + threadIdx.x;
  if (i < N_NODES) {
    int excl = row_ptr[i] - cnt[i] + blk_sums[blockIdx.x];
    row_ptr[i] = excl;
    cursor[i] = excl;
  }
}

__global__ void k_scatter(const int* __restrict__ src, const int* __restrict__ dst,
                          int* __restrict__ cursor, int* __restrict__ csr_src) {
  int e = blockIdx.x * 256 + threadIdx.x;
  if (e < N_EDGES) {
    int pos = atomicAdd(&cursor[dst[e]], 1);
    csr_src[pos] = src[e];
  }
}

// ---------------- neighbor aggregation (one wave per node) ----------------
__global__ __launch_bounds__(256) void k_aggregate(
    const float* __restrict__ h, const int* __restrict__ row_ptr,
    const int* __restrict__ csr_src, float* __restrict__ agg) {
  int node = blockIdx.x * 4 + (threadIdx.x >> 6);
  if (node >= N_NODES) return;
  int lane = threadIdx.x & 63;
  int s = row_ptr[node], e = row_ptr[node + 1];
  float ax = 0.f, ay = 0.f;
  for (int p = s; p < e; ++p) {
    int j = csr_src[p];
    float2 v = *(const float2*)(h + (size_t)j * FDIM + lane * 2);
    ax += v.x;
    ay += v.y;
  }
  *(float2*)(agg + (size_t)node * FDIM + lane * 2) = make_float2(ax, ay);
}

// ---------------- fused dual GEMM: out = relu(agg@Wrel^T + h@Wroot^T + b) -------
// Tile: 64 rows x 128 cols, K = 2x128 processed as 8 chunks of 32.
__global__ __launch_bounds__(256) void k_gemm_fused(
    const float* __restrict__ Aagg, const float* __restrict__ Ah,
    const float* __restrict__ Wrel, const float* __restrict__ Wroot,
    const float* __restrict__ bias, float* __restrict__ out) {
  __shared__ float As[64][33];    // +1 pad: conflict-free column reads
  __shared__ float Bs[32][132];   // row stride 528B (16B aligned)
  int tid = threadIdx.x;
  int row0 = blockIdx.x * 64;
  int cg = tid & 15, rg = tid >> 4;
  int c0 = cg * 8, r0 = rg * 4;
  float acc[4][8];
#pragma unroll
  for (int i = 0; i < 4; ++i)
#pragma unroll
    for (int j = 0; j < 8; ++j) acc[i][j] = 0.f;

#pragma unroll
  for (int chunk = 0; chunk < 8; ++chunk) {
    const float* Ap = (chunk < 4) ? Aagg : Ah;
    const float* Bp = (chunk < 4) ? Wrel : Wroot;
    int k0 = (chunk & 3) * 32;
    // stage A tile: 64x32 f32, two float4 per thread
    {
      int r = tid >> 2;
      int cc = (tid & 3) * 8;
      int grow = row0 + r;
      if (grow > N_NODES - 1) grow = N_NODES - 1;
      float4 d0 = *(const float4*)(Ap + (size_t)grow * FDIM + k0 + cc);
      float4 d1 = *(const float4*)(Ap + (size_t)grow * FDIM + k0 + cc + 4);
      As[r][cc + 0] = d0.x; As[r][cc + 1] = d0.y;
      As[r][cc + 2] = d0.z; As[r][cc + 3] = d0.w;
      As[r][cc + 4] = d1.x; As[r][cc + 5] = d1.y;
      As[r][cc + 6] = d1.z; As[r][cc + 7] = d1.w;
    }
    // stage B tile transposed: Bs[k][c] = W[c][k0+k]; 128 cols x 32 k = 4096 floats
#pragma unroll
    for (int it = 0; it < 4; ++it) {
      int idx = tid + it * 256;        // 0..1023
      int c = idx >> 3;                // 0..127
      int kk = (idx & 7) * 4;          // 0..28
      float4 d = *(const float4*)(Bp + (size_t)c * FDIM + k0 + kk);
      Bs[kk + 0][c] = d.x;
      Bs[kk + 1][c] = d.y;
      Bs[kk + 2][c] = d.z;
      Bs[kk + 3][c] = d.w;
    }
    __syncthreads();
#pragma unroll
    for (int k = 0; k < 32; ++k) {
      float a0 = As[r0 + 0][k], a1 = As[r0 + 1][k];
      float a2 = As[r0 + 2][k], a3 = As[r0 + 3][k];
      float4 b0 = *(const float4*)&Bs[k][c0];
      float4 b1 = *(const float4*)&Bs[k][c0 + 4];
      float bb[8] = {b0.x, b0.y, b0.z, b0.w, b1.x, b1.y, b1.z, b1.w};
#pragma unroll
      for (int j = 0; j < 8; ++j) {
        acc[0][j] += a0 * bb[j];
        acc[1][j] += a1 * bb[j];
        acc[2][j] += a2 * bb[j];
        acc[3][j] += a3 * bb[j];
      }
    }
    __syncthreads();
  }
  float bv[8];
#pragma unroll
  for (int j = 0; j < 8; ++j) bv[j] = bias[c0 + j];
#pragma unroll
  for (int i = 0; i < 4; ++i) {
    int r = row0 + r0 + i;
    if (r < N_NODES) {
      float4 o0, o1;
      o0.x = fmaxf(acc[i][0] + bv[0], 0.f);
      o0.y = fmaxf(acc[i][1] + bv[1], 0.f);
      o0.z = fmaxf(acc[i][2] + bv[2], 0.f);
      o0.w = fmaxf(acc[i][3] + bv[3], 0.f);
      o1.x = fmaxf(acc[i][4] + bv[4], 0.f);
      o1.y = fmaxf(acc[i][5] + bv[5], 0.f);
      o1.z = fmaxf(acc[i][6] + bv[6], 0.f);
      o1.w = fmaxf(acc[i][7] + bv[7], 0.f);
      *(float4*)(out + (size_t)r * FDIM + c0) = o0;
      *(float4*)(out + (size_t)r * FDIM + c0 + 4) = o1;
    }
  }
}

// ---------------- global mean pool (batch sorted) ----------------
__global__ __launch_bounds__(256) void k_pool(
    const float* __restrict__ h, const int* __restrict__ batch,
    float* __restrict__ pooled) {
  __shared__ int sb[2];
  __shared__ float red[256];
  int g = blockIdx.x;
  if (threadIdx.x < 2) {
    int key = g + (int)threadIdx.x;
    int lo = 0, hi = N_NODES;
    while (lo < hi) {
      int mid = (lo + hi) >> 1;
      if (batch[mid] < key) lo = mid + 1; else hi = mid;
    }
    sb[threadIdx.x] = lo;
  }
  __syncthreads();
  int s0 = sb[0], s1 = sb[1];
  int f = threadIdx.x & 127;
  int half = threadIdx.x >> 7;
  float acc = 0.f;
  for (int i = s0 + half; i < s1; i += 2)
    acc += h[(size_t)i * FDIM + f];
  red[threadIdx.x] = acc;
  __syncthreads();
  if (half == 0) {
    float v = red[f] + red[f + 128];
    float cnt = (float)(s1 - s0);
    pooled[g * FDIM + f] = v / fmaxf(cnt, 1.f);
  }
}

// ---------------- MLP head + log_softmax ----------------
__global__ __launch_bounds__(128) void k_head(
    const float* __restrict__ pooled,
    const float* __restrict__ Wl1, const float* __restrict__ bl1,
    const float* __restrict__ Wl2, const float* __restrict__ bl2,
    float* __restrict__ out) {
  int g = blockIdx.x;
  __shared__ float p[128];
  __shared__ float h1[64];
  __shared__ float logit[CDIM];
  p[threadIdx.x] = pooled[g * FDIM + threadIdx.x];
  __syncthreads();
  if (threadIdx.x < 64) {
    float acc = bl1[threadIdx.x];
    for (int k = 0; k < 128; ++k) acc += p[k] * Wl1[threadIdx.x * 128 + k];
    h1[threadIdx.x] = fmaxf(acc, 0.f);
  }
  __syncthreads();
  if (threadIdx.x < CDIM) {
    float acc = bl2[threadIdx.x];
    for (int k = 0; k < 64; ++k) acc += h1[k] * Wl2[threadIdx.x * 64 + k];
    logit[threadIdx.x] = acc;
  }
  __syncthreads();
  if (threadIdx.x == 0) {
    float m = -1e30f;
    for (int c = 0; c < CDIM; ++c) m = fmaxf(m, logit[c]);
    float s = 0.f;
    for (int c = 0; c < CDIM; ++c) s += expf(logit[c] - m);
    float ls = logf(s);
    for (int c = 0; c < CDIM; ++c) out[g * CDIM + c] = logit[c] - m - ls;
  }
}

extern "C" void kernel_launch(void* const* d_in, const int* in_sizes, int n_in,
                              void* d_out, int out_size, void* d_ws, size_t ws_size,
                              hipStream_t stream) {
  const float* x      = (const float*)d_in[0];
  const int* edge_idx = (const int*)d_in[1];
  const int* batch    = (const int*)d_in[2];
  const float* W1_rel  = (const float*)d_in[4];
  const float* b1_rel  = (const float*)d_in[5];
  const float* W1_root = (const float*)d_in[6];
  const float* W2_rel  = (const float*)d_in[7];
  const float* b2_rel  = (const float*)d_in[8];
  const float* W2_root = (const float*)d_in[9];
  const float* W3_rel  = (const float*)d_in[10];
  const float* b3_rel  = (const float*)d_in[11];
  const float* W3_root = (const float*)d_in[12];
  const float* Wl1     = (const float*)d_in[13];
  const float* bl1     = (const float*)d_in[14];
  const float* Wl2     = (const float*)d_in[15];
  const float* bl2     = (const float*)d_in[16];
  const int* esrc = edge_idx;
  const int* edst = edge_idx + N_EDGES;

  char* ws = (char*)d_ws;
  size_t off = 0;
  auto alloc = [&](size_t bytes) {
    void* p = ws + off;
    off += (bytes + 255) & ~(size_t)255;
    return p;
  };
  int* row_ptr  = (int*)alloc((N_NODES + 1) * sizeof(int));
  int* cnt      = (int*)alloc(N_NODES * sizeof(int));
  int* cursor   = (int*)alloc(N_NODES * sizeof(int));
  int* blk_sums = (int*)alloc(128 * sizeof(int));
  int* csr_src  = (int*)alloc(N_EDGES * sizeof(int));
  float* aggb   = (float*)alloc((size_t)N_NODES * FDIM * sizeof(float));
  float* hbuf   = (float*)alloc((size_t)N_NODES * FDIM * sizeof(float));
  float* pooled = (float*)alloc(GDIM * FDIM * sizeof(float));

  int nblk = (N_NODES + 1023) / 1024;  // 98
  hipMemsetAsync(cnt, 0, N_NODES * sizeof(int), stream);
  k_hist<<<(N_EDGES + 255) / 256, 256, 0, stream>>>(edst, cnt);
  k_scan_blk<<<nblk, 1024, 0, stream>>>(cnt, row_ptr, blk_sums);
  k_scan_sums<<<1, 128, 0, stream>>>(blk_sums, row_ptr, nblk);
  k_scan_final<<<nblk, 1024, 0, stream>>>(cnt, row_ptr, cursor, blk_sums);
  k_scatter<<<(N_EDGES + 255) / 256, 256, 0, stream>>>(esrc, edst, cursor, csr_src);

  int agg_grid = (N_NODES + 3) / 4;
  int gemm_grid = (N_NODES + 63) / 64;

  // layer 1
  k_aggregate<<<agg_grid, 256, 0, stream>>>(x, row_ptr, csr_src, aggb);
  k_gemm_fused<<<gemm_grid, 256, 0, stream>>>(aggb, x, W1_rel, W1_root, b1_rel, hbuf);
  // layer 2 (in-place over hbuf is safe: each block reads only its own rows)
  k_aggregate<<<agg_grid, 256, 0, stream>>>(hbuf, row_ptr, csr_src, aggb);
  k_gemm_fused<<<gemm_grid, 256, 0, stream>>>(aggb, hbuf, W2_rel, W2_root, b2_rel, hbuf);
  // layer 3
  k_aggregate<<<agg_grid, 256, 0, stream>>>(hbuf, row_ptr, csr_src, aggb);
  k_gemm_fused<<<gemm_grid, 256, 0, stream>>>(aggb, hbuf, W3_rel, W3_root, b3_rel, hbuf);

  k_pool<<<GDIM, 256, 0, stream>>>(hbuf, batch, pooled);
  k_head<<<GDIM, 128, 0, stream>>>(pooled, Wl1, bl1, Wl2, bl2, (float*)d_out);
}

// Round 3
// 1175.107 us; speedup vs baseline: 19.0000x; 19.0000x over previous
//
#include <hip/hip_runtime.h>

#define N_NODES 100000
#define N_EDGES 1600000
#define FDIM 128
#define GDIM 64
#define CDIM 10

// ---------------- CSR build ----------------
__global__ void k_hist(const int* __restrict__ dst, int* __restrict__ cnt) {
  int e = blockIdx.x * 256 + threadIdx.x;
  if (e < N_EDGES) atomicAdd(&cnt[dst[e]], 1);
}

__global__ void k_scan_blk(const int* __restrict__ cnt, int* __restrict__ incl,
                           int* __restrict__ blk_sums) {
  __shared__ int smem[1024];
  int i = blockIdx.x * 1024 + threadIdx.x;
  int v = (i < N_NODES) ? cnt[i] : 0;
  smem[threadIdx.x] = v;
  __syncthreads();
  for (int off = 1; off < 1024; off <<= 1) {
    int t = (threadIdx.x >= off) ? smem[threadIdx.x - off] : 0;
    __syncthreads();
    smem[threadIdx.x] += t;
    __syncthreads();
  }
  if (i < N_NODES) incl[i] = smem[threadIdx.x];
  if (threadIdx.x == 1023) blk_sums[blockIdx.x] = smem[1023];
}

__global__ void k_scan_sums(int* __restrict__ blk_sums, int* __restrict__ row_ptr,
                            int nblk) {
  __shared__ int smem[128];
  int v = (threadIdx.x < nblk) ? blk_sums[threadIdx.x] : 0;
  smem[threadIdx.x] = v;
  __syncthreads();
  for (int off = 1; off < 128; off <<= 1) {
    int t = (threadIdx.x >= off) ? smem[threadIdx.x - off] : 0;
    __syncthreads();
    smem[threadIdx.x] += t;
    __syncthreads();
  }
  if (threadIdx.x < nblk) blk_sums[threadIdx.x] = smem[threadIdx.x] - v;  // exclusive
  if (threadIdx.x == 127) row_ptr[N_NODES] = smem[127];
}

__global__ void k_scan_final(const int* __restrict__ cnt, int* __restrict__ row_ptr,
                             int* __restrict__ cursor, const int* __restrict__ blk_sums) {
  int i = blockIdx.x * 1024 + threadIdx.x;
  if (i < N_NODES) {
    int excl = row_ptr[i] - cnt[i] + blk_sums[blockIdx.x];
    row_ptr[i] = excl;
    cursor[i] = excl;
  }
}

__global__ void k_scatter(const int* __restrict__ src, const int* __restrict__ dst,
                          int* __restrict__ cursor, int* __restrict__ csr_src) {
  int e = blockIdx.x * 256 + threadIdx.x;
  if (e < N_EDGES) {
    int pos = atomicAdd(&cursor[dst[e]], 1);
    csr_src[pos] = src[e];
  }
}

// ---------------- neighbor aggregation (32 lanes per node, float4) ----------------
__global__ __launch_bounds__(256) void k_aggregate(
    const float* __restrict__ h, const int* __restrict__ row_ptr,
    const int* __restrict__ csr_src, float* __restrict__ agg) {
  int node = blockIdx.x * 8 + (threadIdx.x >> 5);
  if (node >= N_NODES) return;
  int lane = threadIdx.x & 31;
  int s = row_ptr[node], e = row_ptr[node + 1];
  float ax = 0.f, ay = 0.f, az = 0.f, aw = 0.f;
  for (int p = s; p < e; ++p) {
    int j = csr_src[p];
    float4 v = *(const float4*)(h + (size_t)j * FDIM + lane * 4);
    ax += v.x; ay += v.y; az += v.z; aw += v.w;
  }
  *(float4*)(agg + (size_t)node * FDIM + lane * 4) = make_float4(ax, ay, az, aw);
}

// ---------------- fused dual GEMM: out = relu(agg@Wrel^T + h@Wroot^T + b) -------
// Tile: 64 rows x 128 cols, K = 2x128 processed as 8 chunks of 32.
// NOTE: chunk loop MUST NOT unroll — r2's explicit unroll hoisted all global
// staging loads, hit the 256-VGPR cap, and spilled 12.5 GB/dispatch to scratch.
__global__ __launch_bounds__(256) void k_gemm_fused(
    const float* __restrict__ Aagg, const float* __restrict__ Ah,
    const float* __restrict__ Wrel, const float* __restrict__ Wroot,
    const float* __restrict__ bias, float* __restrict__ out) {
  __shared__ float As[64][33];    // stride 33: column reads land on 8 banks, 2-way (free)
  __shared__ float Bs[32][132];   // row stride 528B (16B aligned for float4 reads)
  int tid = threadIdx.x;
  int row0 = blockIdx.x * 64;
  int cg = tid & 15, rg = tid >> 4;
  int c0 = cg * 8, r0 = rg * 4;
  float acc[4][8];
#pragma unroll
  for (int i = 0; i < 4; ++i)
#pragma unroll
    for (int j = 0; j < 8; ++j) acc[i][j] = 0.f;

#pragma unroll 1
  for (int chunk = 0; chunk < 8; ++chunk) {
    const float* Ap = (chunk < 4) ? Aagg : Ah;
    const float* Bp = (chunk < 4) ? Wrel : Wroot;
    int k0 = (chunk & 3) * 32;
    // stage A tile: 64x32 f32, two float4 per thread
    {
      int r = tid >> 2;
      int cc = (tid & 3) * 8;
      int grow = row0 + r;
      if (grow > N_NODES - 1) grow = N_NODES - 1;
      float4 d0 = *(const float4*)(Ap + (size_t)grow * FDIM + k0 + cc);
      float4 d1 = *(const float4*)(Ap + (size_t)grow * FDIM + k0 + cc + 4);
      As[r][cc + 0] = d0.x; As[r][cc + 1] = d0.y;
      As[r][cc + 2] = d0.z; As[r][cc + 3] = d0.w;
      As[r][cc + 4] = d1.x; As[r][cc + 5] = d1.y;
      As[r][cc + 6] = d1.z; As[r][cc + 7] = d1.w;
    }
    // stage B tile transposed: Bs[k][c] = W[c][k0+k]; 128 cols x 32 k
#pragma unroll
    for (int it = 0; it < 4; ++it) {
      int idx = tid + it * 256;        // 0..1023
      int c = idx >> 3;                // 0..127
      int kk = (idx & 7) * 4;          // 0..28
      float4 d = *(const float4*)(Bp + (size_t)c * FDIM + k0 + kk);
      Bs[kk + 0][c] = d.x;
      Bs[kk + 1][c] = d.y;
      Bs[kk + 2][c] = d.z;
      Bs[kk + 3][c] = d.w;
    }
    __syncthreads();
#pragma unroll 4
    for (int k = 0; k < 32; ++k) {
      float a0 = As[r0 + 0][k], a1 = As[r0 + 1][k];
      float a2 = As[r0 + 2][k], a3 = As[r0 + 3][k];
      float4 b0 = *(const float4*)&Bs[k][c0];
      float4 b1 = *(const float4*)&Bs[k][c0 + 4];
      acc[0][0] += a0 * b0.x; acc[0][1] += a0 * b0.y;
      acc[0][2] += a0 * b0.z; acc[0][3] += a0 * b0.w;
      acc[0][4] += a0 * b1.x; acc[0][5] += a0 * b1.y;
      acc[0][6] += a0 * b1.z; acc[0][7] += a0 * b1.w;
      acc[1][0] += a1 * b0.x; acc[1][1] += a1 * b0.y;
      acc[1][2] += a1 * b0.z; acc[1][3] += a1 * b0.w;
      acc[1][4] += a1 * b1.x; acc[1][5] += a1 * b1.y;
      acc[1][6] += a1 * b1.z; acc[1][7] += a1 * b1.w;
      acc[2][0] += a2 * b0.x; acc[2][1] += a2 * b0.y;
      acc[2][2] += a2 * b0.z; acc[2][3] += a2 * b0.w;
      acc[2][4] += a2 * b1.x; acc[2][5] += a2 * b1.y;
      acc[2][6] += a2 * b1.z; acc[2][7] += a2 * b1.w;
      acc[3][0] += a3 * b0.x; acc[3][1] += a3 * b0.y;
      acc[3][2] += a3 * b0.z; acc[3][3] += a3 * b0.w;
      acc[3][4] += a3 * b1.x; acc[3][5] += a3 * b1.y;
      acc[3][6] += a3 * b1.z; acc[3][7] += a3 * b1.w;
    }
    __syncthreads();
  }
  float bv[8];
#pragma unroll
  for (int j = 0; j < 8; ++j) bv[j] = bias[c0 + j];
#pragma unroll
  for (int i = 0; i < 4; ++i) {
    int r = row0 + r0 + i;
    if (r < N_NODES) {
      float4 o0, o1;
      o0.x = fmaxf(acc[i][0] + bv[0], 0.f);
      o0.y = fmaxf(acc[i][1] + bv[1], 0.f);
      o0.z = fmaxf(acc[i][2] + bv[2], 0.f);
      o0.w = fmaxf(acc[i][3] + bv[3], 0.f);
      o1.x = fmaxf(acc[i][4] + bv[4], 0.f);
      o1.y = fmaxf(acc[i][5] + bv[5], 0.f);
      o1.z = fmaxf(acc[i][6] + bv[6], 0.f);
      o1.w = fmaxf(acc[i][7] + bv[7], 0.f);
      *(float4*)(out + (size_t)r * FDIM + c0) = o0;
      *(float4*)(out + (size_t)r * FDIM + c0 + 4) = o1;
    }
  }
}

// ---------------- global mean pool (batch sorted) ----------------
__global__ __launch_bounds__(256) void k_pool(
    const float* __restrict__ h, const int* __restrict__ batch,
    float* __restrict__ pooled) {
  __shared__ int sb[2];
  __shared__ float red[256];
  int g = blockIdx.x;
  if (threadIdx.x < 2) {
    int key = g + (int)threadIdx.x;
    int lo = 0, hi = N_NODES;
    while (lo < hi) {
      int mid = (lo + hi) >> 1;
      if (batch[mid] < key) lo = mid + 1; else hi = mid;
    }
    sb[threadIdx.x] = lo;
  }
  __syncthreads();
  int s0 = sb[0], s1 = sb[1];
  int f = threadIdx.x & 127;
  int half = threadIdx.x >> 7;
  float acc = 0.f;
  for (int i = s0 + half; i < s1; i += 2)
    acc += h[(size_t)i * FDIM + f];
  red[threadIdx.x] = acc;
  __syncthreads();
  if (half == 0) {
    float v = red[f] + red[f + 128];
    float cnt = (float)(s1 - s0);
    pooled[g * FDIM + f] = v / fmaxf(cnt, 1.f);
  }
}

// ---------------- MLP head + log_softmax ----------------
__global__ __launch_bounds__(128) void k_head(
    const float* __restrict__ pooled,
    const float* __restrict__ Wl1, const float* __restrict__ bl1,
    const float* __restrict__ Wl2, const float* __restrict__ bl2,
    float* __restrict__ out) {
  int g = blockIdx.x;
  __shared__ float p[128];
  __shared__ float h1[64];
  __shared__ float logit[CDIM];
  p[threadIdx.x] = pooled[g * FDIM + threadIdx.x];
  __syncthreads();
  if (threadIdx.x < 64) {
    float acc = bl1[threadIdx.x];
    for (int k = 0; k < 128; ++k) acc += p[k] * Wl1[threadIdx.x * 128 + k];
    h1[threadIdx.x] = fmaxf(acc, 0.f);
  }
  __syncthreads();
  if (threadIdx.x < CDIM) {
    float acc = bl2[threadIdx.x];
    for (int k = 0; k < 64; ++k) acc += h1[k] * Wl2[threadIdx.x * 64 + k];
    logit[threadIdx.x] = acc;
  }
  __syncthreads();
  if (threadIdx.x == 0) {
    float m = -1e30f;
    for (int c = 0; c < CDIM; ++c) m = fmaxf(m, logit[c]);
    float s = 0.f;
    for (int c = 0; c < CDIM; ++c) s += expf(logit[c] - m);
    float ls = logf(s);
    for (int c = 0; c < CDIM; ++c) out[g * CDIM + c] = logit[c] - m - ls;
  }
}

extern "C" void kernel_launch(void* const* d_in, const int* in_sizes, int n_in,
                              void* d_out, int out_size, void* d_ws, size_t ws_size,
                              hipStream_t stream) {
  const float* x      = (const float*)d_in[0];
  const int* edge_idx = (const int*)d_in[1];
  const int* batch    = (const int*)d_in[2];
  const float* W1_rel  = (const float*)d_in[4];
  const float* b1_rel  = (const float*)d_in[5];
  const float* W1_root = (const float*)d_in[6];
  const float* W2_rel  = (const float*)d_in[7];
  const float* b2_rel  = (const float*)d_in[8];
  const float* W2_root = (const float*)d_in[9];
  const float* W3_rel  = (const float*)d_in[10];
  const float* b3_rel  = (const float*)d_in[11];
  const float* W3_root = (const float*)d_in[12];
  const float* Wl1     = (const float*)d_in[13];
  const float* bl1     = (const float*)d_in[14];
  const float* Wl2     = (const float*)d_in[15];
  const float* bl2     = (const float*)d_in[16];
  const int* esrc = edge_idx;
  const int* edst = edge_idx + N_EDGES;

  char* ws = (char*)d_ws;
  size_t off = 0;
  auto alloc = [&](size_t bytes) {
    void* p = ws + off;
    off += (bytes + 255) & ~(size_t)255;
    return p;
  };
  int* row_ptr  = (int*)alloc((N_NODES + 1) * sizeof(int));
  int* cnt      = (int*)alloc(N_NODES * sizeof(int));
  int* cursor   = (int*)alloc(N_NODES * sizeof(int));
  int* blk_sums = (int*)alloc(128 * sizeof(int));
  int* csr_src  = (int*)alloc(N_EDGES * sizeof(int));
  float* aggb   = (float*)alloc((size_t)N_NODES * FDIM * sizeof(float));
  float* hbuf   = (float*)alloc((size_t)N_NODES * FDIM * sizeof(float));
  float* pooled = (float*)alloc(GDIM * FDIM * sizeof(float));

  int nblk = (N_NODES + 1023) / 1024;  // 98
  hipMemsetAsync(cnt, 0, N_NODES * sizeof(int), stream);
  k_hist<<<(N_EDGES + 255) / 256, 256, 0, stream>>>(edst, cnt);
  k_scan_blk<<<nblk, 1024, 0, stream>>>(cnt, row_ptr, blk_sums);
  k_scan_sums<<<1, 128, 0, stream>>>(blk_sums, row_ptr, nblk);
  k_scan_final<<<nblk, 1024, 0, stream>>>(cnt, row_ptr, cursor, blk_sums);
  k_scatter<<<(N_EDGES + 255) / 256, 256, 0, stream>>>(esrc, edst, cursor, csr_src);

  int agg_grid = (N_NODES + 7) / 8;
  int gemm_grid = (N_NODES + 63) / 64;

  // layer 1
  k_aggregate<<<agg_grid, 256, 0, stream>>>(x, row_ptr, csr_src, aggb);
  k_gemm_fused<<<gemm_grid, 256, 0, stream>>>(aggb, x, W1_rel, W1_root, b1_rel, hbuf);
  // layer 2 (in-place over hbuf is safe: each block reads only its own rows)
  k_aggregate<<<agg_grid, 256, 0, stream>>>(hbuf, row_ptr, csr_src, aggb);
  k_gemm_fused<<<gemm_grid, 256, 0, stream>>>(aggb, hbuf, W2_rel, W2_root, b2_rel, hbuf);
  // layer 3
  k_aggregate<<<agg_grid, 256, 0, stream>>>(hbuf, row_ptr, csr_src, aggb);
  k_gemm_fused<<<gemm_grid, 256, 0, stream>>>(aggb, hbuf, W3_rel, W3_root, b3_rel, hbuf);

  k_pool<<<GDIM, 256, 0, stream>>>(hbuf, batch, pooled);
  k_head<<<GDIM, 128, 0, stream>>>(pooled, Wl1, bl1, Wl2, bl2, (float*)d_out);
}

// Round 4
// 1020.275 us; speedup vs baseline: 21.8833x; 1.1518x over previous
//
#include <hip/hip_runtime.h>

#define N_NODES 100000
#define N_EDGES 1600000
#define FDIM 128
#define GDIM 64
#define CDIM 10

// ---------------- CSR build ----------------
__global__ void k_hist(const int* __restrict__ dst, int* __restrict__ cnt) {
  int e = blockIdx.x * 256 + threadIdx.x;
  if (e < N_EDGES) atomicAdd(&cnt[dst[e]], 1);
}

__global__ void k_scan_blk(const int* __restrict__ cnt, int* __restrict__ incl,
                           int* __restrict__ blk_sums) {
  __shared__ int smem[1024];
  int i = blockIdx.x * 1024 + threadIdx.x;
  int v = (i < N_NODES) ? cnt[i] : 0;
  smem[threadIdx.x] = v;
  __syncthreads();
  for (int off = 1; off < 1024; off <<= 1) {
    int t = (threadIdx.x >= off) ? smem[threadIdx.x - off] : 0;
    __syncthreads();
    smem[threadIdx.x] += t;
    __syncthreads();
  }
  if (i < N_NODES) incl[i] = smem[threadIdx.x];
  if (threadIdx.x == 1023) blk_sums[blockIdx.x] = smem[1023];
}

__global__ void k_scan_sums(int* __restrict__ blk_sums, int* __restrict__ row_ptr,
                            int nblk) {
  __shared__ int smem[128];
  int v = (threadIdx.x < nblk) ? blk_sums[threadIdx.x] : 0;
  smem[threadIdx.x] = v;
  __syncthreads();
  for (int off = 1; off < 128; off <<= 1) {
    int t = (threadIdx.x >= off) ? smem[threadIdx.x - off] : 0;
    __syncthreads();
    smem[threadIdx.x] += t;
    __syncthreads();
  }
  if (threadIdx.x < nblk) blk_sums[threadIdx.x] = smem[threadIdx.x] - v;  // exclusive
  if (threadIdx.x == 127) row_ptr[N_NODES] = smem[127];
}

__global__ void k_scan_final(const int* __restrict__ cnt, int* __restrict__ row_ptr,
                             int* __restrict__ cursor, const int* __restrict__ blk_sums) {
  int i = blockIdx.x * 1024 + threadIdx.x;
  if (i < N_NODES) {
    int excl = row_ptr[i] - cnt[i] + blk_sums[blockIdx.x];
    row_ptr[i] = excl;
    cursor[i] = excl;
  }
}

__global__ void k_scatter(const int* __restrict__ src, const int* __restrict__ dst,
                          int* __restrict__ cursor, int* __restrict__ csr_src) {
  int e = blockIdx.x * 256 + threadIdx.x;
  if (e < N_EDGES) {
    int pos = atomicAdd(&cursor[dst[e]], 1);
    csr_src[pos] = src[e];
  }
}

// ---------------- neighbor aggregation (32 lanes per node, float4) ----------------
__global__ __launch_bounds__(256) void k_aggregate(
    const float* __restrict__ h, const int* __restrict__ row_ptr,
    const int* __restrict__ csr_src, float* __restrict__ agg) {
  int node = blockIdx.x * 8 + (threadIdx.x >> 5);
  if (node >= N_NODES) return;
  int lane = threadIdx.x & 31;
  int s = row_ptr[node], e = row_ptr[node + 1];
  float ax = 0.f, ay = 0.f, az = 0.f, aw = 0.f;
  for (int p = s; p < e; ++p) {
    int j = csr_src[p];
    float4 v = *(const float4*)(h + (size_t)j * FDIM + lane * 4);
    ax += v.x; ay += v.y; az += v.z; aw += v.w;
  }
  *(float4*)(agg + (size_t)node * FDIM + lane * 4) = make_float4(ax, ay, az, aw);
}

// ---------------- fused dual GEMM: out = relu(agg@Wrel^T + h@Wroot^T + b) -------
// Tile: 64 rows x 128 cols, K = 2x128 processed as 8 chunks of 32.
// NOTE: chunk loop MUST NOT unroll — r2's explicit unroll hoisted all global
// staging loads, hit the 256-VGPR cap, and spilled 12.5 GB/dispatch to scratch.
__global__ __launch_bounds__(256) void k_gemm_fused(
    const float* __restrict__ Aagg, const float* __restrict__ Ah,
    const float* __restrict__ Wrel, const float* __restrict__ Wroot,
    const float* __restrict__ bias, float* __restrict__ out) {
  __shared__ float As[64][33];    // stride 33: column reads land on 8 banks, 2-way (free)
  __shared__ float Bs[32][132];   // row stride 528B (16B aligned for float4 reads)
  int tid = threadIdx.x;
  int row0 = blockIdx.x * 64;
  int cg = tid & 15, rg = tid >> 4;
  int c0 = cg * 8, r0 = rg * 4;
  float acc[4][8];
#pragma unroll
  for (int i = 0; i < 4; ++i)
#pragma unroll
    for (int j = 0; j < 8; ++j) acc[i][j] = 0.f;

#pragma unroll 1
  for (int chunk = 0; chunk < 8; ++chunk) {
    const float* Ap = (chunk < 4) ? Aagg : Ah;
    const float* Bp = (chunk < 4) ? Wrel : Wroot;
    int k0 = (chunk & 3) * 32;
    // stage A tile: 64x32 f32, two float4 per thread
    {
      int r = tid >> 2;
      int cc = (tid & 3) * 8;
      int grow = row0 + r;
      if (grow > N_NODES - 1) grow = N_NODES - 1;
      float4 d0 = *(const float4*)(Ap + (size_t)grow * FDIM + k0 + cc);
      float4 d1 = *(const float4*)(Ap + (size_t)grow * FDIM + k0 + cc + 4);
      As[r][cc + 0] = d0.x; As[r][cc + 1] = d0.y;
      As[r][cc + 2] = d0.z; As[r][cc + 3] = d0.w;
      As[r][cc + 4] = d1.x; As[r][cc + 5] = d1.y;
      As[r][cc + 6] = d1.z; As[r][cc + 7] = d1.w;
    }
    // stage B tile transposed: Bs[k][c] = W[c][k0+k]; 128 cols x 32 k
#pragma unroll
    for (int it = 0; it < 4; ++it) {
      int idx = tid + it * 256;        // 0..1023
      int c = idx >> 3;                // 0..127
      int kk = (idx & 7) * 4;          // 0..28
      float4 d = *(const float4*)(Bp + (size_t)c * FDIM + k0 + kk);
      Bs[kk + 0][c] = d.x;
      Bs[kk + 1][c] = d.y;
      Bs[kk + 2][c] = d.z;
      Bs[kk + 3][c] = d.w;
    }
    __syncthreads();
#pragma unroll 4
    for (int k = 0; k < 32; ++k) {
      float a0 = As[r0 + 0][k], a1 = As[r0 + 1][k];
      float a2 = As[r0 + 2][k], a3 = As[r0 + 3][k];
      float4 b0 = *(const float4*)&Bs[k][c0];
      float4 b1 = *(const float4*)&Bs[k][c0 + 4];
      acc[0][0] += a0 * b0.x; acc[0][1] += a0 * b0.y;
      acc[0][2] += a0 * b0.z; acc[0][3] += a0 * b0.w;
      acc[0][4] += a0 * b1.x; acc[0][5] += a0 * b1.y;
      acc[0][6] += a0 * b1.z; acc[0][7] += a0 * b1.w;
      acc[1][0] += a1 * b0.x; acc[1][1] += a1 * b0.y;
      acc[1][2] += a1 * b0.z; acc[1][3] += a1 * b0.w;
      acc[1][4] += a1 * b1.x; acc[1][5] += a1 * b1.y;
      acc[1][6] += a1 * b1.z; acc[1][7] += a1 * b1.w;
      acc[2][0] += a2 * b0.x; acc[2][1] += a2 * b0.y;
      acc[2][2] += a2 * b0.z; acc[2][3] += a2 * b0.w;
      acc[2][4] += a2 * b1.x; acc[2][5] += a2 * b1.y;
      acc[2][6] += a2 * b1.z; acc[2][7] += a2 * b1.w;
      acc[3][0] += a3 * b0.x; acc[3][1] += a3 * b0.y;
      acc[3][2] += a3 * b0.z; acc[3][3] += a3 * b0.w;
      acc[3][4] += a3 * b1.x; acc[3][5] += a3 * b1.y;
      acc[3][6] += a3 * b1.z; acc[3][7] += a3 * b1.w;
    }
    __syncthreads();
  }
  float bv[8];
#pragma unroll
  for (int j = 0; j < 8; ++j) bv[j] = bias[c0 + j];
#pragma unroll
  for (int i = 0; i < 4; ++i) {
    int r = row0 + r0 + i;
    if (r < N_NODES) {
      float4 o0, o1;
      o0.x = fmaxf(acc[i][0] + bv[0], 0.f);
      o0.y = fmaxf(acc[i][1] + bv[1], 0.f);
      o0.z = fmaxf(acc[i][2] + bv[2], 0.f);
      o0.w = fmaxf(acc[i][3] + bv[3], 0.f);
      o1.x = fmaxf(acc[i][4] + bv[4], 0.f);
      o1.y = fmaxf(acc[i][5] + bv[5], 0.f);
      o1.z = fmaxf(acc[i][6] + bv[6], 0.f);
      o1.w = fmaxf(acc[i][7] + bv[7], 0.f);
      *(float4*)(out + (size_t)r * FDIM + c0) = o0;
      *(float4*)(out + (size_t)r * FDIM + c0 + 4) = o1;
    }
  }
}

// ---------------- global mean pool phase 1: partial sums via transition-flush ----
// batch is sorted; each thread keeps (gcur, acc4) and atomicAdds only when the
// graph id changes within its node stride (<=2 flushes typical per thread).
#define POOL_CHUNK 256
__global__ __launch_bounds__(256) void k_pool_partial(
    const float* __restrict__ h, const int* __restrict__ batch,
    float* __restrict__ pooled) {
  int start = blockIdx.x * POOL_CHUNK;
  int end = start + POOL_CHUNK;
  if (end > N_NODES) end = N_NODES;
  int lane = threadIdx.x & 31;   // feature group: 4 floats
  int slot = threadIdx.x >> 5;   // 0..7 node slots
  int f = lane * 4;
  float4 acc = make_float4(0.f, 0.f, 0.f, 0.f);
  int gcur = -1;
  for (int i = start + slot; i < end; i += 8) {
    int g = batch[i];
    float4 v = *(const float4*)(h + (size_t)i * FDIM + f);
    if (g != gcur) {
      if (gcur >= 0) {
        float* p = pooled + (size_t)gcur * FDIM + f;
        atomicAdd(p + 0, acc.x); atomicAdd(p + 1, acc.y);
        atomicAdd(p + 2, acc.z); atomicAdd(p + 3, acc.w);
      }
      acc = make_float4(0.f, 0.f, 0.f, 0.f);
      gcur = g;
    }
    acc.x += v.x; acc.y += v.y; acc.z += v.z; acc.w += v.w;
  }
  if (gcur >= 0) {
    float* p = pooled + (size_t)gcur * FDIM + f;
    atomicAdd(p + 0, acc.x); atomicAdd(p + 1, acc.y);
    atomicAdd(p + 2, acc.z); atomicAdd(p + 3, acc.w);
  }
}

// ---------------- MLP head + log_softmax (divides pooled sums by counts) -------
__global__ __launch_bounds__(128) void k_head(
    const float* __restrict__ pooled, const int* __restrict__ batch,
    const float* __restrict__ Wl1, const float* __restrict__ bl1,
    const float* __restrict__ Wl2, const float* __restrict__ bl2,
    float* __restrict__ out) {
  int g = blockIdx.x;
  __shared__ int sb[2];
  __shared__ float p[128];
  __shared__ float h1[64];
  __shared__ float logit[CDIM];
  if (threadIdx.x < 2) {
    int key = g + (int)threadIdx.x;
    int lo = 0, hi = N_NODES;
    while (lo < hi) {
      int mid = (lo + hi) >> 1;
      if (batch[mid] < key) lo = mid + 1; else hi = mid;
    }
    sb[threadIdx.x] = lo;
  }
  __syncthreads();
  float cnt = (float)(sb[1] - sb[0]);
  p[threadIdx.x] = pooled[g * FDIM + threadIdx.x] / fmaxf(cnt, 1.f);
  __syncthreads();
  if (threadIdx.x < 64) {
    float acc = bl1[threadIdx.x];
    for (int k = 0; k < 128; ++k) acc += p[k] * Wl1[threadIdx.x * 128 + k];
    h1[threadIdx.x] = fmaxf(acc, 0.f);
  }
  __syncthreads();
  if (threadIdx.x < CDIM) {
    float acc = bl2[threadIdx.x];
    for (int k = 0; k < 64; ++k) acc += h1[k] * Wl2[threadIdx.x * 64 + k];
    logit[threadIdx.x] = acc;
  }
  __syncthreads();
  if (threadIdx.x == 0) {
    float m = -1e30f;
    for (int c = 0; c < CDIM; ++c) m = fmaxf(m, logit[c]);
    float s = 0.f;
    for (int c = 0; c < CDIM; ++c) s += expf(logit[c] - m);
    float ls = logf(s);
    for (int c = 0; c < CDIM; ++c) out[g * CDIM + c] = logit[c] - m - ls;
  }
}

extern "C" void kernel_launch(void* const* d_in, const int* in_sizes, int n_in,
                              void* d_out, int out_size, void* d_ws, size_t ws_size,
                              hipStream_t stream) {
  const float* x      = (const float*)d_in[0];
  const int* edge_idx = (const int*)d_in[1];
  const int* batch    = (const int*)d_in[2];
  const float* W1_rel  = (const float*)d_in[4];
  const float* b1_rel  = (const float*)d_in[5];
  const float* W1_root = (const float*)d_in[6];
  const float* W2_rel  = (const float*)d_in[7];
  const float* b2_rel  = (const float*)d_in[8];
  const float* W2_root = (const float*)d_in[9];
  const float* W3_rel  = (const float*)d_in[10];
  const float* b3_rel  = (const float*)d_in[11];
  const float* W3_root = (const float*)d_in[12];
  const float* Wl1     = (const float*)d_in[13];
  const float* bl1     = (const float*)d_in[14];
  const float* Wl2     = (const float*)d_in[15];
  const float* bl2     = (const float*)d_in[16];
  const int* esrc = edge_idx;
  const int* edst = edge_idx + N_EDGES;

  char* ws = (char*)d_ws;
  size_t off = 0;
  auto alloc = [&](size_t bytes) {
    void* p = ws + off;
    off += (bytes + 255) & ~(size_t)255;
    return p;
  };
  int* row_ptr  = (int*)alloc((N_NODES + 1) * sizeof(int));
  int* cnt      = (int*)alloc(N_NODES * sizeof(int));
  int* cursor   = (int*)alloc(N_NODES * sizeof(int));
  int* blk_sums = (int*)alloc(128 * sizeof(int));
  int* csr_src  = (int*)alloc(N_EDGES * sizeof(int));
  float* aggb   = (float*)alloc((size_t)N_NODES * FDIM * sizeof(float));
  float* hbuf   = (float*)alloc((size_t)N_NODES * FDIM * sizeof(float));
  float* pooled = (float*)alloc(GDIM * FDIM * sizeof(float));

  int nblk = (N_NODES + 1023) / 1024;  // 98
  hipMemsetAsync(cnt, 0, N_NODES * sizeof(int), stream);
  hipMemsetAsync(pooled, 0, GDIM * FDIM * sizeof(float), stream);
  k_hist<<<(N_EDGES + 255) / 256, 256, 0, stream>>>(edst, cnt);
  k_scan_blk<<<nblk, 1024, 0, stream>>>(cnt, row_ptr, blk_sums);
  k_scan_sums<<<1, 128, 0, stream>>>(blk_sums, row_ptr, nblk);
  k_scan_final<<<nblk, 1024, 0, stream>>>(cnt, row_ptr, cursor, blk_sums);
  k_scatter<<<(N_EDGES + 255) / 256, 256, 0, stream>>>(esrc, edst, cursor, csr_src);

  int agg_grid = (N_NODES + 7) / 8;
  int gemm_grid = (N_NODES + 63) / 64;

  // layer 1
  k_aggregate<<<agg_grid, 256, 0, stream>>>(x, row_ptr, csr_src, aggb);
  k_gemm_fused<<<gemm_grid, 256, 0, stream>>>(aggb, x, W1_rel, W1_root, b1_rel, hbuf);
  // layer 2 (in-place over hbuf is safe: each block reads only its own rows)
  k_aggregate<<<agg_grid, 256, 0, stream>>>(hbuf, row_ptr, csr_src, aggb);
  k_gemm_fused<<<gemm_grid, 256, 0, stream>>>(aggb, hbuf, W2_rel, W2_root, b2_rel, hbuf);
  // layer 3
  k_aggregate<<<agg_grid, 256, 0, stream>>>(hbuf, row_ptr, csr_src, aggb);
  k_gemm_fused<<<gemm_grid, 256, 0, stream>>>(aggb, hbuf, W3_rel, W3_root, b3_rel, hbuf);

  int pool_grid = (N_NODES + POOL_CHUNK - 1) / POOL_CHUNK;
  k_pool_partial<<<pool_grid, 256, 0, stream>>>(hbuf, batch, pooled);
  k_head<<<GDIM, 128, 0, stream>>>(pooled, batch, Wl1, bl1, Wl2, bl2, (float*)d_out);
}

// Round 5
// 734.428 us; speedup vs baseline: 30.4005x; 1.3892x over previous
//
#include <hip/hip_runtime.h>

#define N_NODES 100000
#define NPAD    100032      // rounded up to 64 so GEMM blocks need no row clamp
#define N_EDGES 1600000
#define FDIM 128
#define GDIM 64
#define CDIM 10

typedef unsigned short us16;
typedef us16 usx4 __attribute__((ext_vector_type(4)));
typedef us16 usx8 __attribute__((ext_vector_type(8)));
typedef short bfrag __attribute__((ext_vector_type(8)));   // 8 bf16 = 4 VGPRs
typedef float f32x4 __attribute__((ext_vector_type(4)));

__device__ __forceinline__ float bf2f(us16 u) {
  return __uint_as_float(((unsigned)u) << 16);
}
__device__ __forceinline__ us16 f2bf(float f) {
  unsigned u = __float_as_uint(f);
  u += 0x7FFFu + ((u >> 16) & 1u);   // RNE
  return (us16)(u >> 16);
}

// ---------------- CSR build ----------------
__global__ void k_hist(const int* __restrict__ dst, int* __restrict__ cnt) {
  int e = blockIdx.x * 256 + threadIdx.x;
  if (e < N_EDGES) atomicAdd(&cnt[dst[e]], 1);
}

__global__ void k_scan_blk(const int* __restrict__ cnt, int* __restrict__ incl,
                           int* __restrict__ blk_sums) {
  __shared__ int smem[1024];
  int i = blockIdx.x * 1024 + threadIdx.x;
  int v = (i < N_NODES) ? cnt[i] : 0;
  smem[threadIdx.x] = v;
  __syncthreads();
  for (int off = 1; off < 1024; off <<= 1) {
    int t = (threadIdx.x >= off) ? smem[threadIdx.x - off] : 0;
    __syncthreads();
    smem[threadIdx.x] += t;
    __syncthreads();
  }
  if (i < N_NODES) incl[i] = smem[threadIdx.x];
  if (threadIdx.x == 1023) blk_sums[blockIdx.x] = smem[1023];
}

__global__ void k_scan_sums(int* __restrict__ blk_sums, int* __restrict__ row_ptr,
                            int nblk) {
  __shared__ int smem[128];
  int v = (threadIdx.x < nblk) ? blk_sums[threadIdx.x] : 0;
  smem[threadIdx.x] = v;
  __syncthreads();
  for (int off = 1; off < 128; off <<= 1) {
    int t = (threadIdx.x >= off) ? smem[threadIdx.x - off] : 0;
    __syncthreads();
    smem[threadIdx.x] += t;
    __syncthreads();
  }
  if (threadIdx.x < nblk) blk_sums[threadIdx.x] = smem[threadIdx.x] - v;  // exclusive
  if (threadIdx.x == 127) row_ptr[N_NODES] = smem[127];
}

__global__ void k_scan_final(const int* __restrict__ cnt, int* __restrict__ row_ptr,
                             int* __restrict__ cursor, const int* __restrict__ blk_sums) {
  int i = blockIdx.x * 1024 + threadIdx.x;
  if (i < N_NODES) {
    int excl = row_ptr[i] - cnt[i] + blk_sums[blockIdx.x];
    row_ptr[i] = excl;
    cursor[i] = excl;
  }
}

__global__ void k_scatter(const int* __restrict__ src, const int* __restrict__ dst,
                          int* __restrict__ cursor, int* __restrict__ csr_src) {
  int e = blockIdx.x * 256 + threadIdx.x;
  if (e < N_EDGES) {
    int pos = atomicAdd(&cursor[dst[e]], 1);
    csr_src[pos] = src[e];
  }
}

// ---------------- fp32 -> bf16 casts ----------------
__global__ __launch_bounds__(256) void k_cast_x(const float* __restrict__ x,
                                                us16* __restrict__ xb) {
  int i = blockIdx.x * 256 + threadIdx.x;             // group of 4 floats
  if (i >= N_NODES * FDIM / 4) return;
  float4 v = ((const float4*)x)[i];
  usx4 o;
  o[0] = f2bf(v.x); o[1] = f2bf(v.y); o[2] = f2bf(v.z); o[3] = f2bf(v.w);
  *(usx4*)(xb + (size_t)i * 4) = o;
}

// Pack weights into MFMA b-fragment order: Wp[l][kq][col][j], kq=k>>3 (k=0..255,
// k<128 -> Wrel, k>=128 -> Wroot), so a lane's b_frag is one contiguous 16B read.
__global__ __launch_bounds__(256) void k_cast_w(
    const float* __restrict__ Wrel1, const float* __restrict__ Wroot1,
    const float* __restrict__ Wrel2, const float* __restrict__ Wroot2,
    const float* __restrict__ Wrel3, const float* __restrict__ Wroot3,
    us16* __restrict__ Wp) {
  int l = blockIdx.y;
  const float* Wrel  = (l == 0) ? Wrel1  : (l == 1) ? Wrel2  : Wrel3;
  const float* Wroot = (l == 0) ? Wroot1 : (l == 1) ? Wroot2 : Wroot3;
  int idx = blockIdx.x * 256 + threadIdx.x;   // 0..32767
  int k = idx >> 7;       // 0..255
  int c = idx & 127;      // output col
  float v = (k < 128) ? Wrel[c * 128 + k] : Wroot[c * 128 + k - 128];
  Wp[(size_t)l * 32768 + (((k >> 3) * 128 + c) << 3) + (k & 7)] = f2bf(v);
}

// ---------------- neighbor aggregation (bf16 in/out, fp32 accum) --------------
__global__ __launch_bounds__(256) void k_aggregate_b(
    const us16* __restrict__ h, const int* __restrict__ row_ptr,
    const int* __restrict__ csr_src, us16* __restrict__ agg) {
  int node = blockIdx.x * 8 + (threadIdx.x >> 5);
  if (node >= N_NODES) return;
  int lane = threadIdx.x & 31;
  int s = row_ptr[node], e = row_ptr[node + 1];
  const us16* base = h + lane * 4;
  float a0 = 0.f, a1 = 0.f, a2 = 0.f, a3 = 0.f;
  for (int p = s; p < e; ++p) {
    int j = csr_src[p];
    usx4 v = *(const usx4*)(base + (size_t)j * FDIM);
    a0 += bf2f(v[0]); a1 += bf2f(v[1]); a2 += bf2f(v[2]); a3 += bf2f(v[3]);
  }
  usx4 o;
  o[0] = f2bf(a0); o[1] = f2bf(a1); o[2] = f2bf(a2); o[3] = f2bf(a3);
  *(usx4*)(agg + (size_t)node * FDIM + lane * 4) = o;
}

// ---------------- MFMA dual GEMM: out = relu([agg|h] @ [Wrel|Wroot]^T + b) ----
// Block: 256 thr = 4 waves, 64 rows. Wave w owns rows [64b+16w .. +15] for both
// reads and writes -> in-place over hbuf is race-free. Buffers padded to NPAD
// rows so tail blocks read (discarded) pad rows instead of clamping.
__global__ __launch_bounds__(256) void k_gemm_mfma(
    const us16* __restrict__ Aagg, const us16* __restrict__ Ah,
    const us16* __restrict__ Wp, const float* __restrict__ bias,
    us16* __restrict__ out) {
  __shared__ us16 Wl[32768];   // 64 KB: [kq 0..31][col 0..127][j 0..7]
  int tid = threadIdx.x;
  {
    const usx8* s = (const usx8*)Wp;
    usx8* d = (usx8*)Wl;
#pragma unroll
    for (int it = 0; it < 16; ++it) {
      int idx = it * 256 + tid;
      d[idx] = s[idx];
    }
  }
  __syncthreads();
  int wave = tid >> 6, lane = tid & 63;
  int m = lane & 15, quad = lane >> 4;
  size_t rowA = (size_t)(blockIdx.x * 64 + wave * 16 + m);
  const us16* baseAgg = Aagg + rowA * FDIM + quad * 8;
  const us16* baseH   = Ah   + rowA * FDIM + quad * 8;
  f32x4 acc[8];
#pragma unroll
  for (int t = 0; t < 8; ++t) acc[t] = (f32x4){0.f, 0.f, 0.f, 0.f};

#pragma unroll 1
  for (int c = 0; c < 8; ++c) {
    const us16* ap = (c < 4) ? (baseAgg + c * 32) : (baseH + (c - 4) * 32);
    bfrag a = *(const bfrag*)ap;
    int kq = c * 4 + quad;
    const us16* wbase = Wl + (((size_t)kq * 128 + m) << 3);
#pragma unroll
    for (int t = 0; t < 8; ++t) {
      bfrag b = *(const bfrag*)(wbase + t * 128);   // 16 cols * 8 j
      acc[t] = __builtin_amdgcn_mfma_f32_16x16x32_bf16(a, b, acc[t], 0, 0, 0);
    }
  }
  // epilogue: D lane mapping col = lane&15, row = quad*4 + i
  int orow0 = blockIdx.x * 64 + wave * 16 + quad * 4;
#pragma unroll
  for (int t = 0; t < 8; ++t) {
    int col = t * 16 + m;
    float bv = bias[col];
#pragma unroll
    for (int i = 0; i < 4; ++i) {
      int r = orow0 + i;
      if (r < N_NODES)
        out[(size_t)r * FDIM + col] = f2bf(fmaxf(acc[t][i] + bv, 0.f));
    }
  }
}

// ---------------- global mean pool phase 1 (bf16 in, fp32 atomics) ------------
#define POOL_CHUNK 256
__global__ __launch_bounds__(256) void k_pool_partial(
    const us16* __restrict__ h, const int* __restrict__ batch,
    float* __restrict__ pooled) {
  int start = blockIdx.x * POOL_CHUNK;
  int end = start + POOL_CHUNK;
  if (end > N_NODES) end = N_NODES;
  int lane = threadIdx.x & 31;
  int slot = threadIdx.x >> 5;
  int f = lane * 4;
  float4 acc = make_float4(0.f, 0.f, 0.f, 0.f);
  int gcur = -1;
  for (int i = start + slot; i < end; i += 8) {
    int g = batch[i];
    usx4 v = *(const usx4*)(h + (size_t)i * FDIM + f);
    if (g != gcur) {
      if (gcur >= 0) {
        float* p = pooled + (size_t)gcur * FDIM + f;
        atomicAdd(p + 0, acc.x); atomicAdd(p + 1, acc.y);
        atomicAdd(p + 2, acc.z); atomicAdd(p + 3, acc.w);
      }
      acc = make_float4(0.f, 0.f, 0.f, 0.f);
      gcur = g;
    }
    acc.x += bf2f(v[0]); acc.y += bf2f(v[1]);
    acc.z += bf2f(v[2]); acc.w += bf2f(v[3]);
  }
  if (gcur >= 0) {
    float* p = pooled + (size_t)gcur * FDIM + f;
    atomicAdd(p + 0, acc.x); atomicAdd(p + 1, acc.y);
    atomicAdd(p + 2, acc.z); atomicAdd(p + 3, acc.w);
  }
}

// ---------------- MLP head + log_softmax ----------------
__global__ __launch_bounds__(128) void k_head(
    const float* __restrict__ pooled, const int* __restrict__ batch,
    const float* __restrict__ Wl1, const float* __restrict__ bl1,
    const float* __restrict__ Wl2, const float* __restrict__ bl2,
    float* __restrict__ out) {
  int g = blockIdx.x;
  __shared__ int sb[2];
  __shared__ float p[128];
  __shared__ float h1[64];
  __shared__ float logit[CDIM];
  if (threadIdx.x < 2) {
    int key = g + (int)threadIdx.x;
    int lo = 0, hi = N_NODES;
    while (lo < hi) {
      int mid = (lo + hi) >> 1;
      if (batch[mid] < key) lo = mid + 1; else hi = mid;
    }
    sb[threadIdx.x] = lo;
  }
  __syncthreads();
  float cnt = (float)(sb[1] - sb[0]);
  p[threadIdx.x] = pooled[g * FDIM + threadIdx.x] / fmaxf(cnt, 1.f);
  __syncthreads();
  if (threadIdx.x < 64) {
    float acc = bl1[threadIdx.x];
    for (int k = 0; k < 128; ++k) acc += p[k] * Wl1[threadIdx.x * 128 + k];
    h1[threadIdx.x] = fmaxf(acc, 0.f);
  }
  __syncthreads();
  if (threadIdx.x < CDIM) {
    float acc = bl2[threadIdx.x];
    for (int k = 0; k < 64; ++k) acc += h1[k] * Wl2[threadIdx.x * 64 + k];
    logit[threadIdx.x] = acc;
  }
  __syncthreads();
  if (threadIdx.x == 0) {
    float m = -1e30f;
    for (int c = 0; c < CDIM; ++c) m = fmaxf(m, logit[c]);
    float s = 0.f;
    for (int c = 0; c < CDIM; ++c) s += expf(logit[c] - m);
    float ls = logf(s);
    for (int c = 0; c < CDIM; ++c) out[g * CDIM + c] = logit[c] - m - ls;
  }
}

extern "C" void kernel_launch(void* const* d_in, const int* in_sizes, int n_in,
                              void* d_out, int out_size, void* d_ws, size_t ws_size,
                              hipStream_t stream) {
  const float* x      = (const float*)d_in[0];
  const int* edge_idx = (const int*)d_in[1];
  const int* batch    = (const int*)d_in[2];
  const float* W1_rel  = (const float*)d_in[4];
  const float* b1_rel  = (const float*)d_in[5];
  const float* W1_root = (const float*)d_in[6];
  const float* W2_rel  = (const float*)d_in[7];
  const float* b2_rel  = (const float*)d_in[8];
  const float* W2_root = (const float*)d_in[9];
  const float* W3_rel  = (const float*)d_in[10];
  const float* b3_rel  = (const float*)d_in[11];
  const float* W3_root = (const float*)d_in[12];
  const float* Wl1     = (const float*)d_in[13];
  const float* bl1     = (const float*)d_in[14];
  const float* Wl2     = (const float*)d_in[15];
  const float* bl2     = (const float*)d_in[16];
  const int* esrc = edge_idx;
  const int* edst = edge_idx + N_EDGES;

  char* ws = (char*)d_ws;
  size_t off = 0;
  auto alloc = [&](size_t bytes) {
    void* p = ws + off;
    off += (bytes + 255) & ~(size_t)255;
    return p;
  };
  int* row_ptr  = (int*)alloc((N_NODES + 1) * sizeof(int));
  int* cnt      = (int*)alloc(N_NODES * sizeof(int));
  int* cursor   = (int*)alloc(N_NODES * sizeof(int));
  int* blk_sums = (int*)alloc(128 * sizeof(int));
  int* csr_src  = (int*)alloc(N_EDGES * sizeof(int));
  us16* xb      = (us16*)alloc((size_t)NPAD * FDIM * sizeof(us16));
  us16* aggb    = (us16*)alloc((size_t)NPAD * FDIM * sizeof(us16));
  us16* hbuf    = (us16*)alloc((size_t)NPAD * FDIM * sizeof(us16));
  us16* Wp      = (us16*)alloc(3 * 32768 * sizeof(us16));
  float* pooled = (float*)alloc(GDIM * FDIM * sizeof(float));

  int nblk = (N_NODES + 1023) / 1024;  // 98
  hipMemsetAsync(cnt, 0, N_NODES * sizeof(int), stream);
  hipMemsetAsync(pooled, 0, GDIM * FDIM * sizeof(float), stream);
  k_hist<<<(N_EDGES + 255) / 256, 256, 0, stream>>>(edst, cnt);
  k_scan_blk<<<nblk, 1024, 0, stream>>>(cnt, row_ptr, blk_sums);
  k_scan_sums<<<1, 128, 0, stream>>>(blk_sums, row_ptr, nblk);
  k_scan_final<<<nblk, 1024, 0, stream>>>(cnt, row_ptr, cursor, blk_sums);
  k_scatter<<<(N_EDGES + 255) / 256, 256, 0, stream>>>(esrc, edst, cursor, csr_src);

  k_cast_x<<<(N_NODES * FDIM / 4 + 255) / 256, 256, 0, stream>>>(x, xb);
  k_cast_w<<<dim3(128, 3), 256, 0, stream>>>(W1_rel, W1_root, W2_rel, W2_root,
                                             W3_rel, W3_root, Wp);

  int agg_grid = (N_NODES + 7) / 8;
  int gemm_grid = NPAD / 64;   // 1563

  // layer 1
  k_aggregate_b<<<agg_grid, 256, 0, stream>>>(xb, row_ptr, csr_src, aggb);
  k_gemm_mfma<<<gemm_grid, 256, 0, stream>>>(aggb, xb, Wp, b1_rel, hbuf);
  // layer 2 (in-place: each wave touches only its own 16 rows)
  k_aggregate_b<<<agg_grid, 256, 0, stream>>>(hbuf, row_ptr, csr_src, aggb);
  k_gemm_mfma<<<gemm_grid, 256, 0, stream>>>(aggb, hbuf, Wp + 32768, b2_rel, hbuf);
  // layer 3
  k_aggregate_b<<<agg_grid, 256, 0, stream>>>(hbuf, row_ptr, csr_src, aggb);
  k_gemm_mfma<<<gemm_grid, 256, 0, stream>>>(aggb, hbuf, Wp + 65536, b3_rel, hbuf);

  int pool_grid = (N_NODES + POOL_CHUNK - 1) / POOL_CHUNK;
  k_pool_partial<<<pool_grid, 256, 0, stream>>>(hbuf, batch, pooled);
  k_head<<<GDIM, 128, 0, stream>>>(pooled, batch, Wl1, bl1, Wl2, bl2, (float*)d_out);
}

// Round 6
// 495.935 us; speedup vs baseline: 45.0200x; 1.4809x over previous
//
#include <hip/hip_runtime.h>

#define N_NODES 100000
#define NPAD    100032      // rounded up to 64 so GEMM blocks need no row clamp
#define N_EDGES 1600000
#define FDIM 128
#define GDIM 64
#define CDIM 10

#define BSH   9
#define BSIZE 512           // nodes per bucket
#define NB    196           // ceil(N_NODES / BSIZE)
#define EPB   8192          // edges per block in bucket passes

typedef unsigned short us16;
typedef us16 usx4 __attribute__((ext_vector_type(4)));
typedef us16 usx8 __attribute__((ext_vector_type(8)));
typedef short bfrag __attribute__((ext_vector_type(8)));   // 8 bf16 = 4 VGPRs
typedef float f32x4 __attribute__((ext_vector_type(4)));

__device__ __forceinline__ float bf2f(us16 u) {
  return __uint_as_float(((unsigned)u) << 16);
}
__device__ __forceinline__ us16 f2bf(float f) {
  unsigned u = __float_as_uint(f);
  u += 0x7FFFu + ((u >> 16) & 1u);   // RNE
  return (us16)(u >> 16);
}

// ---------------- bucketed CSR build ----------------
// Pass A: per-bucket edge counts (LDS histogram, few global atomics)
__global__ __launch_bounds__(256) void k_bhist(const int* __restrict__ dst,
                                               int* __restrict__ bcnt) {
  __shared__ int h[NB];
  int tid = threadIdx.x;
  for (int i = tid; i < NB; i += 256) h[i] = 0;
  __syncthreads();
  int s0 = blockIdx.x * EPB;
  int e0 = s0 + EPB; if (e0 > N_EDGES) e0 = N_EDGES;
  for (int i = s0 + tid; i < e0; i += 256) atomicAdd(&h[dst[i] >> BSH], 1);
  __syncthreads();
  for (int i = tid; i < NB; i += 256)
    if (h[i]) atomicAdd(&bcnt[i], h[i]);
}

// Pass B: scan bucket counts -> offsets + cursors (single block)
__global__ void k_bscan(const int* __restrict__ bcnt, int* __restrict__ boff,
                        int* __restrict__ bcursor, int* __restrict__ row_ptr) {
  __shared__ int sm[256];
  int tid = threadIdx.x;
  int v = (tid < NB) ? bcnt[tid] : 0;
  sm[tid] = v;
  __syncthreads();
  for (int off = 1; off < 256; off <<= 1) {
    int t = (tid >= off) ? sm[tid - off] : 0;
    __syncthreads();
    sm[tid] += t;
    __syncthreads();
  }
  if (tid < NB) { int ex = sm[tid] - v; boff[tid] = ex; bcursor[tid] = ex; }
  if (tid == 0) { boff[NB] = N_EDGES; row_ptr[N_NODES] = N_EDGES; }
}

// Pass C: counting-sort edges into bucket-contiguous (src,dst) runs
__global__ __launch_bounds__(256) void k_bscatter(
    const int* __restrict__ src, const int* __restrict__ dst,
    int* __restrict__ bcursor, int2* __restrict__ ebuf) {
  __shared__ int h[NB];
  __shared__ int base[NB];
  __shared__ int lc[NB];
  int tid = threadIdx.x;
  for (int i = tid; i < NB; i += 256) h[i] = 0;
  __syncthreads();
  int s0 = blockIdx.x * EPB;
  int e0 = s0 + EPB; if (e0 > N_EDGES) e0 = N_EDGES;
  for (int i = s0 + tid; i < e0; i += 256) atomicAdd(&h[dst[i] >> BSH], 1);
  __syncthreads();
  for (int i = tid; i < NB; i += 256) {
    base[i] = h[i] ? atomicAdd(&bcursor[i], h[i]) : 0;
    lc[i] = 0;
  }
  __syncthreads();
  for (int i = s0 + tid; i < e0; i += 256) {
    int d = dst[i];
    int b = d >> BSH;
    int lp = atomicAdd(&lc[b], 1);
    ebuf[base[b] + lp] = make_int2(src[i], d);
  }
}

// Pass D: per-bucket local histogram + Blelloch scan -> row_ptr, then scatter
// srcs with LDS cursors; csr_src writes land in a ~32 KB L2-resident window.
__global__ __launch_bounds__(256) void k_bucket_csr(
    const int2* __restrict__ ebuf, const int* __restrict__ boff,
    int* __restrict__ row_ptr, int* __restrict__ csr_src) {
  __shared__ int hist[BSIZE];
  __shared__ int cur[BSIZE];
  int b = blockIdx.x, tid = threadIdx.x;
  int eoff = boff[b], ecnt = boff[b + 1] - eoff;
  int base = b * BSIZE;
  hist[tid] = 0; hist[tid + 256] = 0;
  __syncthreads();
  for (int i = tid; i < ecnt; i += 256) {
    int2 ed = ebuf[eoff + i];
    atomicAdd(&hist[ed.y - base], 1);
  }
  __syncthreads();
  // Blelloch exclusive scan over 512
  for (int d = 1; d < BSIZE; d <<= 1) {
    int idx = (tid + 1) * (d << 1) - 1;
    if (idx < BSIZE) hist[idx] += hist[idx - d];
    __syncthreads();
  }
  if (tid == 0) hist[BSIZE - 1] = 0;
  __syncthreads();
  for (int d = BSIZE >> 1; d >= 1; d >>= 1) {
    int idx = (tid + 1) * (d << 1) - 1;
    if (idx < BSIZE) {
      int t = hist[idx - d];
      hist[idx - d] = hist[idx];
      hist[idx] += t;
    }
    __syncthreads();
  }
  {
    int n0 = base + tid, n1 = base + tid + 256;
    if (n0 < N_NODES) row_ptr[n0] = eoff + hist[tid];
    if (n1 < N_NODES) row_ptr[n1] = eoff + hist[tid + 256];
    cur[tid] = hist[tid];
    cur[tid + 256] = hist[tid + 256];
  }
  __syncthreads();
  for (int i = tid; i < ecnt; i += 256) {
    int2 ed = ebuf[eoff + i];
    int lp = atomicAdd(&cur[ed.y - base], 1);
    csr_src[eoff + lp] = ed.x;
  }
}

// ---------------- fp32 -> bf16 casts ----------------
__global__ __launch_bounds__(256) void k_cast_x(const float* __restrict__ x,
                                                us16* __restrict__ xb) {
  int i = blockIdx.x * 256 + threadIdx.x;             // group of 4 floats
  if (i >= N_NODES * FDIM / 4) return;
  float4 v = ((const float4*)x)[i];
  usx4 o;
  o[0] = f2bf(v.x); o[1] = f2bf(v.y); o[2] = f2bf(v.z); o[3] = f2bf(v.w);
  *(usx4*)(xb + (size_t)i * 4) = o;
}

// Pack weights into MFMA b-fragment order: Wp[l][kq][col][j], kq=k>>3 (k=0..255,
// k<128 -> Wrel, k>=128 -> Wroot), so a lane's b_frag is one contiguous 16B read.
__global__ __launch_bounds__(256) void k_cast_w(
    const float* __restrict__ Wrel1, const float* __restrict__ Wroot1,
    const float* __restrict__ Wrel2, const float* __restrict__ Wroot2,
    const float* __restrict__ Wrel3, const float* __restrict__ Wroot3,
    us16* __restrict__ Wp) {
  int l = blockIdx.y;
  const float* Wrel  = (l == 0) ? Wrel1  : (l == 1) ? Wrel2  : Wrel3;
  const float* Wroot = (l == 0) ? Wroot1 : (l == 1) ? Wroot2 : Wroot3;
  int idx = blockIdx.x * 256 + threadIdx.x;   // 0..32767
  int k = idx >> 7;       // 0..255
  int c = idx & 127;      // output col
  float v = (k < 128) ? Wrel[c * 128 + k] : Wroot[c * 128 + k - 128];
  Wp[(size_t)l * 32768 + (((k >> 3) * 128 + c) << 3) + (k & 7)] = f2bf(v);
}

// ---------------- neighbor aggregation (16 lanes/node, 16B loads, x4 unroll) --
__global__ __launch_bounds__(256) void k_aggregate_b(
    const us16* __restrict__ h, const int* __restrict__ row_ptr,
    const int* __restrict__ csr_src, us16* __restrict__ agg) {
  int node = blockIdx.x * 16 + (threadIdx.x >> 4);
  if (node >= N_NODES) return;
  int lane = threadIdx.x & 15;
  int s = row_ptr[node], e = row_ptr[node + 1];
  const us16* base = h + lane * 8;
  float a0 = 0.f, a1 = 0.f, a2 = 0.f, a3 = 0.f;
  float a4 = 0.f, a5 = 0.f, a6 = 0.f, a7 = 0.f;
  int p = s;
  for (; p + 4 <= e; p += 4) {
    int j0 = csr_src[p], j1 = csr_src[p + 1];
    int j2 = csr_src[p + 2], j3 = csr_src[p + 3];
    usx8 v0 = *(const usx8*)(base + (size_t)j0 * FDIM);
    usx8 v1 = *(const usx8*)(base + (size_t)j1 * FDIM);
    usx8 v2 = *(const usx8*)(base + (size_t)j2 * FDIM);
    usx8 v3 = *(const usx8*)(base + (size_t)j3 * FDIM);
    a0 += bf2f(v0[0]) + bf2f(v1[0]) + bf2f(v2[0]) + bf2f(v3[0]);
    a1 += bf2f(v0[1]) + bf2f(v1[1]) + bf2f(v2[1]) + bf2f(v3[1]);
    a2 += bf2f(v0[2]) + bf2f(v1[2]) + bf2f(v2[2]) + bf2f(v3[2]);
    a3 += bf2f(v0[3]) + bf2f(v1[3]) + bf2f(v2[3]) + bf2f(v3[3]);
    a4 += bf2f(v0[4]) + bf2f(v1[4]) + bf2f(v2[4]) + bf2f(v3[4]);
    a5 += bf2f(v0[5]) + bf2f(v1[5]) + bf2f(v2[5]) + bf2f(v3[5]);
    a6 += bf2f(v0[6]) + bf2f(v1[6]) + bf2f(v2[6]) + bf2f(v3[6]);
    a7 += bf2f(v0[7]) + bf2f(v1[7]) + bf2f(v2[7]) + bf2f(v3[7]);
  }
  for (; p < e; ++p) {
    int j = csr_src[p];
    usx8 v = *(const usx8*)(base + (size_t)j * FDIM);
    a0 += bf2f(v[0]); a1 += bf2f(v[1]); a2 += bf2f(v[2]); a3 += bf2f(v[3]);
    a4 += bf2f(v[4]); a5 += bf2f(v[5]); a6 += bf2f(v[6]); a7 += bf2f(v[7]);
  }
  usx8 o;
  o[0] = f2bf(a0); o[1] = f2bf(a1); o[2] = f2bf(a2); o[3] = f2bf(a3);
  o[4] = f2bf(a4); o[5] = f2bf(a5); o[6] = f2bf(a6); o[7] = f2bf(a7);
  *(usx8*)(agg + (size_t)node * FDIM + lane * 8) = o;
}

// ---------------- MFMA dual GEMM: out = relu([agg|h] @ [Wrel|Wroot]^T + b) ----
__global__ __launch_bounds__(256) void k_gemm_mfma(
    const us16* __restrict__ Aagg, const us16* __restrict__ Ah,
    const us16* __restrict__ Wp, const float* __restrict__ bias,
    us16* __restrict__ out) {
  __shared__ us16 Wl[32768];   // 64 KB: [kq 0..31][col 0..127][j 0..7]
  int tid = threadIdx.x;
  {
    const usx8* s = (const usx8*)Wp;
    usx8* d = (usx8*)Wl;
#pragma unroll
    for (int it = 0; it < 16; ++it) {
      int idx = it * 256 + tid;
      d[idx] = s[idx];
    }
  }
  __syncthreads();
  int wave = tid >> 6, lane = tid & 63;
  int m = lane & 15, quad = lane >> 4;
  size_t rowA = (size_t)(blockIdx.x * 64 + wave * 16 + m);
  const us16* baseAgg = Aagg + rowA * FDIM + quad * 8;
  const us16* baseH   = Ah   + rowA * FDIM + quad * 8;
  f32x4 acc[8];
#pragma unroll
  for (int t = 0; t < 8; ++t) acc[t] = (f32x4){0.f, 0.f, 0.f, 0.f};

#pragma unroll 1
  for (int c = 0; c < 8; ++c) {
    const us16* ap = (c < 4) ? (baseAgg + c * 32) : (baseH + (c - 4) * 32);
    bfrag a = *(const bfrag*)ap;
    int kq = c * 4 + quad;
    const us16* wbase = Wl + (((size_t)kq * 128 + m) << 3);
#pragma unroll
    for (int t = 0; t < 8; ++t) {
      bfrag b = *(const bfrag*)(wbase + t * 128);   // 16 cols * 8 j
      acc[t] = __builtin_amdgcn_mfma_f32_16x16x32_bf16(a, b, acc[t], 0, 0, 0);
    }
  }
  // epilogue: D lane mapping col = lane&15, row = quad*4 + i
  int orow0 = blockIdx.x * 64 + wave * 16 + quad * 4;
#pragma unroll
  for (int t = 0; t < 8; ++t) {
    int col = t * 16 + m;
    float bv = bias[col];
#pragma unroll
    for (int i = 0; i < 4; ++i) {
      int r = orow0 + i;
      if (r < N_NODES)
        out[(size_t)r * FDIM + col] = f2bf(fmaxf(acc[t][i] + bv, 0.f));
    }
  }
}

// ---------------- global mean pool phase 1 (bf16 in, fp32 atomics) ------------
#define POOL_CHUNK 256
__global__ __launch_bounds__(256) void k_pool_partial(
    const us16* __restrict__ h, const int* __restrict__ batch,
    float* __restrict__ pooled) {
  int start = blockIdx.x * POOL_CHUNK;
  int end = start + POOL_CHUNK;
  if (end > N_NODES) end = N_NODES;
  int lane = threadIdx.x & 31;
  int slot = threadIdx.x >> 5;
  int f = lane * 4;
  float4 acc = make_float4(0.f, 0.f, 0.f, 0.f);
  int gcur = -1;
  for (int i = start + slot; i < end; i += 8) {
    int g = batch[i];
    usx4 v = *(const usx4*)(h + (size_t)i * FDIM + f);
    if (g != gcur) {
      if (gcur >= 0) {
        float* p = pooled + (size_t)gcur * FDIM + f;
        atomicAdd(p + 0, acc.x); atomicAdd(p + 1, acc.y);
        atomicAdd(p + 2, acc.z); atomicAdd(p + 3, acc.w);
      }
      acc = make_float4(0.f, 0.f, 0.f, 0.f);
      gcur = g;
    }
    acc.x += bf2f(v[0]); acc.y += bf2f(v[1]);
    acc.z += bf2f(v[2]); acc.w += bf2f(v[3]);
  }
  if (gcur >= 0) {
    float* p = pooled + (size_t)gcur * FDIM + f;
    atomicAdd(p + 0, acc.x); atomicAdd(p + 1, acc.y);
    atomicAdd(p + 2, acc.z); atomicAdd(p + 3, acc.w);
  }
}

// ---------------- MLP head + log_softmax ----------------
__global__ __launch_bounds__(128) void k_head(
    const float* __restrict__ pooled, const int* __restrict__ batch,
    const float* __restrict__ Wl1, const float* __restrict__ bl1,
    const float* __restrict__ Wl2, const float* __restrict__ bl2,
    float* __restrict__ out) {
  int g = blockIdx.x;
  __shared__ int sb[2];
  __shared__ float p[128];
  __shared__ float h1[64];
  __shared__ float logit[CDIM];
  if (threadIdx.x < 2) {
    int key = g + (int)threadIdx.x;
    int lo = 0, hi = N_NODES;
    while (lo < hi) {
      int mid = (lo + hi) >> 1;
      if (batch[mid] < key) lo = mid + 1; else hi = mid;
    }
    sb[threadIdx.x] = lo;
  }
  __syncthreads();
  float cnt = (float)(sb[1] - sb[0]);
  p[threadIdx.x] = pooled[g * FDIM + threadIdx.x] / fmaxf(cnt, 1.f);
  __syncthreads();
  if (threadIdx.x < 64) {
    float acc = bl1[threadIdx.x];
    for (int k = 0; k < 128; ++k) acc += p[k] * Wl1[threadIdx.x * 128 + k];
    h1[threadIdx.x] = fmaxf(acc, 0.f);
  }
  __syncthreads();
  if (threadIdx.x < CDIM) {
    float acc = bl2[threadIdx.x];
    for (int k = 0; k < 64; ++k) acc += h1[k] * Wl2[threadIdx.x * 64 + k];
    logit[threadIdx.x] = acc;
  }
  __syncthreads();
  if (threadIdx.x == 0) {
    float m = -1e30f;
    for (int c = 0; c < CDIM; ++c) m = fmaxf(m, logit[c]);
    float s = 0.f;
    for (int c = 0; c < CDIM; ++c) s += expf(logit[c] - m);
    float ls = logf(s);
    for (int c = 0; c < CDIM; ++c) out[g * CDIM + c] = logit[c] - m - ls;
  }
}

extern "C" void kernel_launch(void* const* d_in, const int* in_sizes, int n_in,
                              void* d_out, int out_size, void* d_ws, size_t ws_size,
                              hipStream_t stream) {
  const float* x      = (const float*)d_in[0];
  const int* edge_idx = (const int*)d_in[1];
  const int* batch    = (const int*)d_in[2];
  const float* W1_rel  = (const float*)d_in[4];
  const float* b1_rel  = (const float*)d_in[5];
  const float* W1_root = (const float*)d_in[6];
  const float* W2_rel  = (const float*)d_in[7];
  const float* b2_rel  = (const float*)d_in[8];
  const float* W2_root = (const float*)d_in[9];
  const float* W3_rel  = (const float*)d_in[10];
  const float* b3_rel  = (const float*)d_in[11];
  const float* W3_root = (const float*)d_in[12];
  const float* Wl1     = (const float*)d_in[13];
  const float* bl1     = (const float*)d_in[14];
  const float* Wl2     = (const float*)d_in[15];
  const float* bl2     = (const float*)d_in[16];
  const int* esrc = edge_idx;
  const int* edst = edge_idx + N_EDGES;

  char* ws = (char*)d_ws;
  size_t off = 0;
  auto alloc = [&](size_t bytes) {
    void* p = ws + off;
    off += (bytes + 255) & ~(size_t)255;
    return p;
  };
  int* row_ptr  = (int*)alloc((N_NODES + 1) * sizeof(int));
  int* bcnt     = (int*)alloc(NB * sizeof(int));
  int* boff     = (int*)alloc((NB + 1) * sizeof(int));
  int* bcursor  = (int*)alloc(NB * sizeof(int));
  int* csr_src  = (int*)alloc(N_EDGES * sizeof(int));
  us16* xb      = (us16*)alloc((size_t)NPAD * FDIM * sizeof(us16));
  us16* aggb    = (us16*)alloc((size_t)NPAD * FDIM * sizeof(us16));
  us16* hbuf    = (us16*)alloc((size_t)NPAD * FDIM * sizeof(us16));
  us16* Wp      = (us16*)alloc(3 * 32768 * sizeof(us16));
  float* pooled = (float*)alloc(GDIM * FDIM * sizeof(float));
  // ebuf (12.8 MB) aliases hbuf (25.6 MB): dead before gemm-1 writes hbuf
  int2* ebuf    = (int2*)hbuf;

  hipMemsetAsync(bcnt, 0, NB * sizeof(int), stream);
  hipMemsetAsync(pooled, 0, GDIM * FDIM * sizeof(float), stream);

  int bgrid = (N_EDGES + EPB - 1) / EPB;   // 196
  k_bhist<<<bgrid, 256, 0, stream>>>(edst, bcnt);
  k_bscan<<<1, 256, 0, stream>>>(bcnt, boff, bcursor, row_ptr);
  k_bscatter<<<bgrid, 256, 0, stream>>>(esrc, edst, bcursor, ebuf);
  k_bucket_csr<<<NB, 256, 0, stream>>>(ebuf, boff, row_ptr, csr_src);

  k_cast_x<<<(N_NODES * FDIM / 4 + 255) / 256, 256, 0, stream>>>(x, xb);
  k_cast_w<<<dim3(128, 3), 256, 0, stream>>>(W1_rel, W1_root, W2_rel, W2_root,
                                             W3_rel, W3_root, Wp);

  int agg_grid = (N_NODES + 15) / 16;      // 6250
  int gemm_grid = NPAD / 64;               // 1563

  // layer 1
  k_aggregate_b<<<agg_grid, 256, 0, stream>>>(xb, row_ptr, csr_src, aggb);
  k_gemm_mfma<<<gemm_grid, 256, 0, stream>>>(aggb, xb, Wp, b1_rel, hbuf);
  // layer 2 (in-place: each wave touches only its own 16 rows)
  k_aggregate_b<<<agg_grid, 256, 0, stream>>>(hbuf, row_ptr, csr_src, aggb);
  k_gemm_mfma<<<gemm_grid, 256, 0, stream>>>(aggb, hbuf, Wp + 32768, b2_rel, hbuf);
  // layer 3
  k_aggregate_b<<<agg_grid, 256, 0, stream>>>(hbuf, row_ptr, csr_src, aggb);
  k_gemm_mfma<<<gemm_grid, 256, 0, stream>>>(aggb, hbuf, Wp + 65536, b3_rel, hbuf);

  int pool_grid = (N_NODES + POOL_CHUNK - 1) / POOL_CHUNK;
  k_pool_partial<<<pool_grid, 256, 0, stream>>>(hbuf, batch, pooled);
  k_head<<<GDIM, 128, 0, stream>>>(pooled, batch, Wl1, bl1, Wl2, bl2, (float*)d_out);
}